// Round 10
// baseline (109.599 us; speedup 1.0000x reference)
//
#include <hip/hip_runtime.h>
#include <cstddef>
#include <cstdint>

constexpr int B_ = 64, C_ = 128, T_ = 1024, H_ = 512, ENC_ = 512;
#define ALPHA_F 0.9512294245007140f
#define ONEMA_F 0.0487705754992860f

typedef short v8s __attribute__((ext_vector_type(8)));
typedef float v4f __attribute__((ext_vector_type(4)));

#define GL16(gp, lp) __builtin_amdgcn_global_load_lds( \
    (const __attribute__((address_space(1))) unsigned int*)(gp), \
    (__attribute__((address_space(3))) unsigned int*)(lp), 16, 0, 0)

__device__ __forceinline__ unsigned short f2bf(float f) {
    union { float f; unsigned u; } v; v.f = f;
    unsigned r = v.u + 0x7FFFu + ((v.u >> 16) & 1u);
    return (unsigned short)(r >> 16);
}
__device__ __forceinline__ float bf2f(unsigned short h) {
    union { unsigned u; float f; } v; v.u = ((unsigned)h) << 16;
    return v.f;
}

// ---------------------------------------------------------------------------
// k_prep: fused {depthwise conv -> enc bf16} + {cast w1 -> bf16} + {W_eff}.
// grid: [0,2048) conv | [2048,2304) cast | [2304,2432) weff. 256 threads.
// ---------------------------------------------------------------------------
__global__ __launch_bounds__(256) void k_prep(
    const float* __restrict__ x, const float* __restrict__ cw,
    const float* __restrict__ cb, const float* __restrict__ w1,
    const float* __restrict__ w2, const float* __restrict__ b2,
    const float* __restrict__ og, unsigned short* __restrict__ enc,
    unsigned short* __restrict__ w1b, unsigned short* __restrict__ Weffb,
    float* __restrict__ beff)
{
    __shared__ float smem[132 * 33];
    const int bid = blockIdx.x;
    const int tid = threadIdx.x;

    if (bid < 2048) {
        const int b  = bid >> 5;
        const int t0 = ((bid >> 2) & 7) << 7;
        const int c0 = (bid & 3) << 5;
        const int c_l = tid & 31;
        const int tl0 = tid >> 5;
        float (*xs)[33] = (float(*)[33])smem;

        const int c = c0 + c_l;
        float wreg[20];
        {
            const float4* wp = (const float4*)(cw + (size_t)c * 20);
#pragma unroll
            for (int q = 0; q < 5; ++q) {
                const float4 v = wp[q];
                wreg[q * 4 + 0] = v.x; wreg[q * 4 + 1] = v.y;
                wreg[q * 4 + 2] = v.z; wreg[q * 4 + 3] = v.w;
            }
        }
        const float4 breg = *(const float4*)(cb + (size_t)c * 4);

        const float* xrow = x + ((size_t)b * C_ + c0) * T_;
        for (int i = tid; i < 32 * 132; i += 256) {
            const int cc = i / 132;
            const int j  = i - cc * 132;
            const int t  = t0 - 2 + j;
            float v = 0.f;
            if (t >= 0 && t < T_) v = xrow[(size_t)cc * T_ + t];
            xs[j][cc] = v;
        }
        __syncthreads();

        unsigned short* erow = enc + (size_t)(b * T_ + t0) * 512 + c * 4;
#pragma unroll
        for (int tt = 0; tt < 16; ++tt) {
            const int tl = tl0 + (tt << 3);
            const float x0 = xs[tl][c_l],     x1 = xs[tl + 1][c_l],
                        x2 = xs[tl + 2][c_l], x3 = xs[tl + 3][c_l],
                        x4 = xs[tl + 4][c_l];
            ushort4 hv;
            const float a0 = breg.x + wreg[0]*x0 + wreg[1]*x1 + wreg[2]*x2 + wreg[3]*x3 + wreg[4]*x4;
            const float a1 = breg.y + wreg[5]*x0 + wreg[6]*x1 + wreg[7]*x2 + wreg[8]*x3 + wreg[9]*x4;
            const float a2 = breg.z + wreg[10]*x0 + wreg[11]*x1 + wreg[12]*x2 + wreg[13]*x3 + wreg[14]*x4;
            const float a3 = breg.w + wreg[15]*x0 + wreg[16]*x1 + wreg[17]*x2 + wreg[18]*x3 + wreg[19]*x4;
            hv.x = f2bf(a0); hv.y = f2bf(a1); hv.z = f2bf(a2); hv.w = f2bf(a3);
            *(ushort4*)(erow + (size_t)tl * 512) = hv;
        }
    } else if (bid < 2304) {
        const int i = (bid - 2048) * 256 + tid;
        float4 v = ((const float4*)w1)[i];
        ushort4 h;
        h.x = f2bf(v.x); h.y = f2bf(v.y); h.z = f2bf(v.z); h.w = f2bf(v.w);
        ((ushort4*)w1b)[i] = h;
    } else {
        const int c = bid - 2304;
        float* ogs = smem;
        if (tid < 128) {
            float g = og[c * C_ + tid];
            if (tid == c) g = 0.f;
            ogs[tid] = g;
        }
        __syncthreads();
        if (tid < 128) {
            float acc[4];
#pragma unroll
            for (int s = 0; s < 4; ++s) acc[s] = w2[c * H_ + tid + s * 128];
            for (int cp = 0; cp < C_; ++cp) {
                const float w = ogs[cp];
#pragma unroll
                for (int s = 0; s < 4; ++s) acc[s] += w * w2[cp * H_ + tid + s * 128];
            }
#pragma unroll
            for (int s = 0; s < 4; ++s) Weffb[c * H_ + tid + s * 128] = f2bf(acc[s]);
            if (tid == 0) {
                float a = b2[c];
                for (int cp = 0; cp < C_; ++cp) a += ogs[cp] * b2[cp];
                beff[c] = a;
            }
        }
    }
}

// ---------------------------------------------------------------------------
// GEMM1 v4: 256m x 128n tile, BK=32, triple-buffered 72 KB -> 2 blocks/CU.
// 4 waves (2m x 2n), wave tile 128x64 -> MFMA:ds_read = 2.67 (LDS pipe no
// longer the bound: per CU-kt LDS ~1152 cyc < MFMA ~1241 cyc).
// ROTATION swizzle for 64B rows: lds_slot = (q + (row>>1)) & 3 -> rows 0..7
// cover all 8 bank-quads, 8..15 repeat = 2-way (free). Source pre-applies
// the inverse (rule 21). Counted vmcnt(6) (stage kt+2, wait kt+1), 1 barrier
// per K-tile (triple-buffer legality). Grid 1024, bijective XCD swizzle.
// ---------------------------------------------------------------------------
__global__ __launch_bounds__(256, 2) void k_gemm1v4(
    const unsigned short* __restrict__ A, const unsigned short* __restrict__ Bw,
    const float* __restrict__ bias, unsigned short* __restrict__ out)
{
    __shared__ unsigned char lds[73728];  // buf k at k*24576: { A 16K | B 8K }
    const int tid = threadIdx.x;
    const int lane = tid & 63;
    const int w = tid >> 6;         // 0..3
    const int wr = w >> 1;          // m-half: rows wr*128..+127
    const int wc = w & 1;           // n-half: cols wc*64..+63
    const int l15 = lane & 15;
    const int klo = lane >> 4;      // logical k-slot 0..3 (8 elems each)

    const int d = blockIdx.x;                  // 1024 blocks
    const int g = ((d & 7) << 7) | (d >> 3);   // XCD-contiguous (1024%8==0)
    const int m0 = (g >> 2) << 8;
    const int n0 = (g & 3) << 7;

    const int sr = tid >> 2;        // staging base row (tid>>2) + i*64
    const int ssl = tid & 3;        // staging dest slot

    const unsigned char* Ag = (const unsigned char*)A;
    const unsigned char* Bg = (const unsigned char*)Bw;

    v4f acc[8][4];
#pragma unroll
    for (int i = 0; i < 8; ++i)
#pragma unroll
        for (int j = 0; j < 4; ++j) acc[i][j] = (v4f)0.f;

    v8s pa[4], pb[4];

    // stage: A 16 KB (4 chunks) + B 8 KB (2 chunks); dest linear, source
    // slot = (ssl - (row>>1)) & 3  (inverse of the read rotation)
#define STG(sb, ktv) do { \
    _Pragma("unroll") \
    for (int i_ = 0; i_ < 4; ++i_) { \
        const int r_ = sr + i_ * 64; \
        GL16(Ag + (size_t)(m0 + r_) * 1024 + (ktv) * 64 + \
                 (((ssl - (r_ >> 1)) & 3) << 4), \
             lds + (sb) * 24576 + (size_t)(tid + i_ * 256) * 16); \
    } \
    _Pragma("unroll") \
    for (int i_ = 0; i_ < 2; ++i_) { \
        const int r_ = sr + i_ * 64; \
        GL16(Bg + (size_t)(n0 + r_) * 1024 + (ktv) * 64 + \
                 (((ssl - (r_ >> 1)) & 3) << 4), \
             lds + (sb) * 24576 + 16384 + (size_t)(tid + i_ * 256) * 16); \
    } \
} while(0)

#define LDB4(cb) do { \
    _Pragma("unroll") \
    for (int ni_ = 0; ni_ < 4; ++ni_) { \
        const int rb_ = wc * 64 + ni_ * 16 + l15; \
        pb[ni_] = *(const v8s*)(lds + (cb) * 24576 + 16384 + rb_ * 64 + \
            (((klo + (rb_ >> 1)) & 3) << 4)); \
    } \
} while(0)

#define LDA4(cb, h) do { \
    _Pragma("unroll") \
    for (int i_ = 0; i_ < 4; ++i_) { \
        const int ra_ = wr * 128 + ((h) * 4 + i_) * 16 + l15; \
        pa[i_] = *(const v8s*)(lds + (cb) * 24576 + ra_ * 64 + \
            (((klo + (ra_ >> 1)) & 3) << 4)); \
    } \
} while(0)

#define MM16(h) do { \
    __builtin_amdgcn_s_setprio(1); \
    _Pragma("unroll") \
    for (int i_ = 0; i_ < 4; ++i_) \
      _Pragma("unroll") \
      for (int ni_ = 0; ni_ < 4; ++ni_) \
        acc[(h) * 4 + i_][ni_] = __builtin_amdgcn_mfma_f32_16x16x32_bf16( \
            pa[i_], pb[ni_], acc[(h) * 4 + i_][ni_], 0, 0, 0); \
    __builtin_amdgcn_s_setprio(0); \
} while(0)

#define BARX() do { __builtin_amdgcn_sched_barrier(0); \
    __builtin_amdgcn_s_barrier(); \
    __builtin_amdgcn_sched_barrier(0); } while(0)

    // prologue: kt0 -> buf0, kt1 -> buf1; wait kt0 only (kt1 stays in flight)
    STG(0, 0);
    STG(1, 1);
    asm volatile("s_waitcnt vmcnt(6)" ::: "memory");
    BARX();

    for (int kt = 0; kt < 16; ++kt) {
        const int cb = kt % 3;
        const int sb = (kt + 2) % 3;
        LDB4(cb);
        LDA4(cb, 0);
        if (kt <= 13) STG(sb, kt + 2);
        MM16(0);
        LDA4(cb, 1);
        MM16(1);
        if (kt <= 13) {
            asm volatile("s_waitcnt vmcnt(6)" ::: "memory");
        } else {
            asm volatile("s_waitcnt vmcnt(0)" ::: "memory");
        }
        BARX();
    }

    // epilogue: C 256x128 bf16 (64 KB) via LDS, coalesced 256B-row stores
#pragma unroll
    for (int mi = 0; mi < 8; ++mi)
#pragma unroll
        for (int ni = 0; ni < 4; ++ni) {
            const int n = wc * 64 + ni * 16 + l15;
            const float bi = bias[n0 + n];
#pragma unroll
            for (int r = 0; r < 4; ++r) {
                const int m = wr * 128 + mi * 16 + klo * 4 + r;
                *(unsigned short*)(lds + m * 256 +
                    ((2 * n) ^ (((m >> 2) & 3) << 5))) =
                    f2bf(acc[mi][ni][r] + bi);
            }
        }
    BARX();
#pragma unroll
    for (int it = 0; it < 16; ++it) {
        const int idx = it * 256 + tid;       // 0..4095
        const int r = idx >> 4, s = idx & 15;
        const int4 v = *(const int4*)(lds + r * 256 +
            ((s * 16) ^ (((r >> 2) & 3) << 5)));
        *(int4*)(&out[(size_t)(m0 + r) * 512 + n0 + s * 8]) = v;
    }
#undef STG
#undef LDA4
#undef LDB4
#undef MM16
#undef BARX
}

// ---------------------------------------------------------------------------
// k_rg2: FUSED LIF recurrence + GEMM2 (r8-proven). Grid 256 = (b x 4 chunks).
// ---------------------------------------------------------------------------
__global__ __launch_bounds__(256) void k_rg2(
    const unsigned short* __restrict__ hid,
    const unsigned short* __restrict__ Weffb,
    const float* __restrict__ beff, float* __restrict__ out)
{
    __shared__ unsigned char lds[147456];   // mem tile 128 KB | A-chunk 16 KB
    unsigned char* ldsA = lds + 131072;
    const int tid = threadIdx.x;
    const int lane = tid & 63;
    const int w = tid >> 6;
    const int wm = (w & 1) << 6;
    const int wn = (w >> 1) << 6;
    const int l15 = lane & 15, klo = lane >> 4;

    const int b  = blockIdx.x >> 2;
    const int tc = blockIdx.x & 3;
    const int tbase = tc << 8;

    const unsigned int* pin = (const unsigned int*)hid + ((size_t)b << 18) + tid;

    float ma = 0.f, mb = 0.f;

    if (tc > 0) {
        for (int t = tbase - 128; t < tbase; t += 16) {
            unsigned int v[16];
#pragma unroll
            for (int i = 0; i < 16; ++i) v[i] = pin[(size_t)(t + i) << 8];
#pragma unroll
            for (int i = 0; i < 16; ++i) {
                ma = ALPHA_F * ma + ONEMA_F * bf2f((unsigned short)(v[i] & 0xFFFFu));
                ma = (ma >= 1.0f) ? 0.f : ma;
                mb = ALPHA_F * mb + ONEMA_F * bf2f((unsigned short)(v[i] >> 16));
                mb = (mb >= 1.0f) ? 0.f : mb;
            }
        }
    }

    for (int half = 0; half < 2; ++half) {
        const int t0 = tbase + (half << 7);

        for (int t = t0; t < t0 + 128; t += 16) {
            unsigned int v[16];
#pragma unroll
            for (int i = 0; i < 16; ++i) v[i] = pin[(size_t)(t + i) << 8];
#pragma unroll
            for (int i = 0; i < 16; ++i) {
                ma = ALPHA_F * ma + ONEMA_F * bf2f((unsigned short)(v[i] & 0xFFFFu));
                ma = (ma >= 1.0f) ? 0.f : ma;
                mb = ALPHA_F * mb + ONEMA_F * bf2f((unsigned short)(v[i] >> 16));
                mb = (mb >= 1.0f) ? 0.f : mb;
                const unsigned int mv = (unsigned)f2bf(ma) | ((unsigned)f2bf(mb) << 16);
                const int tr = t + i - t0;
                *(unsigned int*)(lds + tr * 1024 + ((tid * 4) ^ ((tr & 7) << 4))) = mv;
            }
        }
        __syncthreads();

        v4f acc[4][4];
#pragma unroll
        for (int i = 0; i < 4; ++i)
#pragma unroll
            for (int j = 0; j < 4; ++j) acc[i][j] = (v4f)0.f;

        for (int k0 = 0; k0 < 512; k0 += 64) {
#pragma unroll
            for (int i_ = 0; i_ < 4; ++i_) {
                const int row = i_ * 32 + (tid >> 3);
                GL16((const unsigned char*)Weffb + (size_t)row * 1024 + k0 * 2 +
                         (((tid & 7) ^ (row & 7)) << 4),
                     ldsA + i_ * 4096 + tid * 16);
            }
            __syncthreads();

#pragma unroll
            for (int ks = 0; ks < 2; ++ks) {
                v8s af[4], bfr[4];
#pragma unroll
                for (int i = 0; i < 4; ++i) {
                    const int ra = wm + i * 16 + l15;
                    const int rt = wn + i * 16 + l15;
                    const int kb = ks * 64 + klo * 16;
                    af[i]  = *(const v8s*)(ldsA + ra * 128 + (kb ^ ((ra & 7) << 4)));
                    bfr[i] = *(const v8s*)(lds + rt * 1024 +
                             ((k0 * 2 + kb) ^ ((rt & 7) << 4)));
                }
                __builtin_amdgcn_s_setprio(1);
#pragma unroll
                for (int mi = 0; mi < 4; ++mi)
#pragma unroll
                    for (int ni = 0; ni < 4; ++ni)
                        acc[mi][ni] = __builtin_amdgcn_mfma_f32_16x16x32_bf16(
                            af[mi], bfr[ni], acc[mi][ni], 0, 0, 0);
                __builtin_amdgcn_s_setprio(0);
            }
            __syncthreads();
        }

#pragma unroll
        for (int mi = 0; mi < 4; ++mi)
#pragma unroll
            for (int ni = 0; ni < 4; ++ni) {
                const int n = wn + ni * 16 + l15;
#pragma unroll
                for (int r = 0; r < 4; ++r) {
                    const int m = wm + mi * 16 + klo * 4 + r;
                    *(float*)(lds + m * 512 + ((n * 4) ^ (((m >> 2) & 3) << 5))) =
                        acc[mi][ni][r] + beff[m];
                }
            }
        __syncthreads();
#pragma unroll
        for (int it = 0; it < 16; ++it) {
            const int idx = it * 256 + tid;
            const int r = idx >> 5, s = idx & 31;
            const int4 v = *(const int4*)(lds + r * 512 +
                ((s * 16) ^ (((r >> 2) & 3) << 5)));
            *(int4*)(&out[((size_t)(b * C_ + r) << 10) + t0 + s * 4]) = v;
        }
        __syncthreads();
    }
}

// ---------------------------------------------------------------------------
extern "C" void kernel_launch(void* const* d_in, const int* in_sizes, int n_in,
                              void* d_out, int out_size, void* d_ws, size_t ws_size,
                              hipStream_t stream)
{
    const float* x   = (const float*)d_in[0];
    const float* cw  = (const float*)d_in[1];
    const float* cb  = (const float*)d_in[2];
    const float* w1  = (const float*)d_in[3];
    const float* b1  = (const float*)d_in[4];
    const float* w2  = (const float*)d_in[5];
    const float* b2  = (const float*)d_in[6];
    const float* og  = (const float*)d_in[7];

    char* ws = (char*)d_ws;
    unsigned short* enc   = (unsigned short*)ws;               // 64 MiB
    unsigned short* hid   = (unsigned short*)(ws + 67108864);  // 64 MiB
    unsigned short* Weffb = (unsigned short*)(ws + 134217728); // 128 KiB
    float*          beff  = (float*)(ws + 134479872);          // 512 B
    unsigned short* w1b   = (unsigned short*)d_out;            // temp, dead before k_rg2

    k_prep<<<2432, 256, 0, stream>>>(x, cw, cb, w1, w2, b2, og,
                                     enc, w1b, Weffb, beff);

    k_gemm1v4<<<1024, 256, 0, stream>>>(enc, w1b, b1, hid);

    k_rg2<<<256, 256, 0, stream>>>(hid, Weffb, beff, (float*)d_out);
}